// Round 9
// baseline (728.687 us; speedup 1.0000x reference)
//
#include <hip/hip_runtime.h>
#include <hip/hip_bf16.h>
#include <math.h>

#define B_ 4
#define S_ 2048
#define D_ 1024
#define H_ 16
#define HD_ 64
#define TRIPLE 3072

typedef __attribute__((ext_vector_type(8))) short bf16x8;
typedef __attribute__((ext_vector_type(4))) float f32x4;
typedef __attribute__((ext_vector_type(8))) unsigned short u16x8;
typedef unsigned short ushort_t;

#define MFMA(a, b, c) __builtin_amdgcn_mfma_f32_16x16x32_bf16((a), (b), (c), 0, 0, 0)

__device__ __forceinline__ ushort_t f2bf(float f) {
    union { float f; unsigned int u; } u; u.f = f;
    unsigned int r = u.u + 0x7fff + ((u.u >> 16) & 1); // RNE
    return (ushort_t)(r >> 16);
}
__device__ __forceinline__ float bf2f(ushort_t h) {
    union { unsigned int u; float f; } u; u.u = ((unsigned int)h) << 16;
    return u.f;
}

// async global->LDS, 16B per lane; LDS dest = wave-uniform base + lane*16
__device__ __forceinline__ void gload16(const ushort_t* g, void* l) {
    __builtin_amdgcn_global_load_lds(
        (const __attribute__((address_space(1))) unsigned int*)g,
        (__attribute__((address_space(3))) unsigned int*)l,
        16, 0, 0);
}

// ---------------------------------------------------------------------------
// fp32 -> bf16 cast, 8 elems/thread
// ---------------------------------------------------------------------------
__global__ __launch_bounds__(256) void castk(const float* __restrict__ s,
                                             ushort_t* __restrict__ d, int n) {
    int i = (blockIdx.x * 256 + threadIdx.x) * 8;
    if (i >= n) return;
    float4 a = *(const float4*)(s + i);
    float4 b = *(const float4*)(s + i + 4);
    u16x8 o;
    o[0] = f2bf(a.x); o[1] = f2bf(a.y); o[2] = f2bf(a.z); o[3] = f2bf(a.w);
    o[4] = f2bf(b.x); o[5] = f2bf(b.y); o[6] = f2bf(b.z); o[7] = f2bf(b.w);
    *(u16x8*)(d + i) = o;
}

// ---------------------------------------------------------------------------
// BF16 MFMA GEMM, m97 structure: 128x128 tile, BK=64, 4 waves,
// global_load_lds width=16 staging into LINEAR LDS (128B rows).
// ---------------------------------------------------------------------------
__global__ __launch_bounds__(256) void gemm_bf16(
    const ushort_t* __restrict__ A, const ushort_t* __restrict__ W,
    const float* __restrict__ bias, ushort_t* __restrict__ C,
    int N, int K, int act)
{
    __shared__ char Asb[128 * 128];
    __shared__ char Wsb[128 * 128];
    const int tid = threadIdx.x;
    const int wv = tid >> 6, lane = tid & 63;
    const int fr = lane & 15, fq = lane >> 4;
    const int wr = wv >> 1, wc = wv & 1;
    const int m0 = blockIdx.y * 128, n0 = blockIdx.x * 128;

    // staging: wave wv covers rows [wv*32, wv*32+32) in 4 chunks of 8 rows;
    // lane l of a chunk: row = +(l>>3), k-bytes = (l&7)*16 (matches HW
    // lds-dest = base + lane*16).
    const int lrow = lane >> 3;
    const int lke  = (lane & 7) * 8;
    const ushort_t* Agl = A + (size_t)(m0 + wv * 32 + lrow) * K + lke;
    const ushort_t* Wgl = W + (size_t)(n0 + wv * 32 + lrow) * K + lke;

    const f32x4 fz = {0.f, 0.f, 0.f, 0.f};
    f32x4 acc[4][4];
    #pragma unroll
    for (int i = 0; i < 4; ++i)
        #pragma unroll
        for (int j = 0; j < 4; ++j) acc[i][j] = fz;

    for (int k0 = 0; k0 < K; k0 += 64) {
        __syncthreads(); // previous tile reads done
        #pragma unroll
        for (int c = 0; c < 4; ++c) {
            gload16(Agl + k0 + c * 8 * K, Asb + (wv * 32 + c * 8) * 128);
            gload16(Wgl + k0 + c * 8 * K, Wsb + (wv * 32 + c * 8) * 128);
        }
        __syncthreads(); // vmcnt drain + barrier (compiler-emitted)
        #pragma unroll
        for (int ks = 0; ks < 2; ++ks) {
            bf16x8 af[4], bfr[4];
            #pragma unroll
            for (int i = 0; i < 4; ++i) {
                af[i]  = *(const bf16x8*)(Asb + (wr * 64 + i * 16 + fr) * 128 + (ks * 4 + fq) * 16);
                bfr[i] = *(const bf16x8*)(Wsb + (wc * 64 + i * 16 + fr) * 128 + (ks * 4 + fq) * 16);
            }
            #pragma unroll
            for (int i = 0; i < 4; ++i)
                #pragma unroll
                for (int j = 0; j < 4; ++j)
                    acc[i][j] = MFMA(af[i], bfr[j], acc[i][j]);
        }
    }

    float bv[4];
    #pragma unroll
    for (int j = 0; j < 4; ++j) bv[j] = bias[n0 + wc * 64 + j * 16 + fr];
    #pragma unroll
    for (int i = 0; i < 4; ++i) {
        #pragma unroll
        for (int j = 0; j < 4; ++j) {
            int col = n0 + wc * 64 + j * 16 + fr;
            #pragma unroll
            for (int r = 0; r < 4; ++r) {
                int row = m0 + wr * 64 + i * 16 + fq * 4 + r;
                float v = acc[i][j][r] + bv[j];
                if (act) v = 0.5f * v * (1.0f + erff(v * 0.70710678118654752f));
                C[(size_t)row * N + col] = f2bf(v);
            }
        }
    }
}

// ---------------------------------------------------------------------------
// V transpose: qkv bf16 [B,S,3D] V-part -> vT [B*H, 64, S] bf16.
// ---------------------------------------------------------------------------
__global__ __launch_bounds__(256) void vtrans(const ushort_t* __restrict__ qkvb,
                                              ushort_t* __restrict__ vT)
{
    __shared__ ushort_t T[64][72];
    const int tid = threadIdx.x;
    const int bh = blockIdx.y;
    const int b = bh >> 4, h = bh & 15;
    const int s0 = blockIdx.x * 64;
    const int r = tid >> 2, q = tid & 3;
    const ushort_t* src = qkvb + (size_t)(b * S_ + s0 + r) * TRIPLE + 2048 + h * 64 + q * 16;
    *(u16x8*)&T[r][q * 16] = *(const u16x8*)(src);
    *(u16x8*)&T[r][q * 16 + 8] = *(const u16x8*)(src + 8);
    __syncthreads();
    u16x8 o0, o1;
    #pragma unroll
    for (int i = 0; i < 8; ++i) o0[i] = T[q * 16 + i][r];
    #pragma unroll
    for (int i = 0; i < 8; ++i) o1[i] = T[q * 16 + 8 + i][r];
    ushort_t* dstp = vT + ((size_t)bh * 64 + r) * S_ + s0 + q * 16;
    *(u16x8*)(dstp) = o0;
    *(u16x8*)(dstp + 8) = o1;
}

// ---------------------------------------------------------------------------
// Flash attention (MFMA), swapped-QK softmax: compute S^T = mfma(K, Q) so each
// lane owns ONE q-row (q = wv*16 + fr) -> row reduce = in-lane + 2 shfl;
// m/l are per-lane scalars; P packed 4 kv/write via cvt_pk + ds_write_b64.
// Defer-max (THR=8) skips O-rescale on most tiles.
// ---------------------------------------------------------------------------
__global__ __launch_bounds__(256) void attn_ctx_mfma(
    const ushort_t* __restrict__ qkvb, const ushort_t* __restrict__ vT,
    ushort_t* __restrict__ ctxb, float* __restrict__ mstat, float* __restrict__ lstat)
{
    __shared__ char Kl[64 * 128];
    __shared__ char Vl[64 * 128];
    __shared__ char Pl[64 * 128];
    const int tid = threadIdx.x;
    const int wv = tid >> 6, lane = tid & 63;
    const int fr = lane & 15, fq = lane >> 4;
    const int fx = fr & 7;
    const int bh = blockIdx.y, b = bh >> 4, h = bh & 15;
    const int q0 = blockIdx.x * 64;
    const int q = wv * 16 + fr; // this lane's q-row for softmax/P

    bf16x8 qf[2];
    {
        const ushort_t* qp = qkvb + (size_t)(b * S_ + q0 + q) * TRIPLE + h * 64 + fq * 8;
        qf[0] = *(const bf16x8*)(qp);
        qf[1] = *(const bf16x8*)(qp + 32);
    }

    const int srow = tid >> 2, sq = tid & 3;
    const ushort_t* Kg = qkvb + (size_t)(b * S_ + srow) * TRIPLE + 1024 + h * 64 + sq * 16;
    const ushort_t* Vg = vT + ((size_t)bh * 64 + srow) * S_ + sq * 16;
    const int sb = srow * 128, sxr = srow & 7;
    const int slot0 = (sq * 2) ^ sxr, slot1 = (sq * 2 + 1) ^ sxr;

    const f32x4 fz = {0.f, 0.f, 0.f, 0.f};
    float m_ = -1e30f, l_ = 0.f;
    f32x4 po[4];
    #pragma unroll
    for (int dn = 0; dn < 4; ++dn) po[dn] = fz;

    for (int k0 = 0; k0 < S_; k0 += 64) {
        u16x8 ks0 = *(const u16x8*)(Kg + (size_t)k0 * TRIPLE);
        u16x8 ks1 = *(const u16x8*)(Kg + (size_t)k0 * TRIPLE + 8);
        u16x8 vs0 = *(const u16x8*)(Vg + k0);
        u16x8 vs1 = *(const u16x8*)(Vg + k0 + 8);
        __syncthreads();
        *(u16x8*)(Kl + sb + slot0 * 16) = ks0;
        *(u16x8*)(Kl + sb + slot1 * 16) = ks1;
        *(u16x8*)(Vl + sb + slot0 * 16) = vs0;
        *(u16x8*)(Vl + sb + slot1 * 16) = vs1;
        __syncthreads();

        // S^T tile: sa[jn][r] = S[kv = jn*16 + fq*4 + r][q]
        f32x4 sa[4];
        #pragma unroll
        for (int jn = 0; jn < 4; ++jn) sa[jn] = fz;
        #pragma unroll
        for (int ks = 0; ks < 2; ++ks) {
            #pragma unroll
            for (int jn = 0; jn < 4; ++jn) {
                int kr = jn * 16 + fr;
                bf16x8 kf = *(const bf16x8*)(Kl + kr * 128 + (((ks * 4 + fq) ^ fx) * 16));
                sa[jn] = MFMA(kf, qf[ks], sa[jn]); // swapped operands
            }
        }

        // per-lane row max over 16 values, then 2 shfl across fq replicas
        float pmax = sa[0][0];
        #pragma unroll
        for (int jn = 0; jn < 4; ++jn)
            #pragma unroll
            for (int r = 0; r < 4; ++r) pmax = fmaxf(pmax, sa[jn][r]);
        pmax *= 0.125f;
        pmax = fmaxf(pmax, __shfl_xor(pmax, 16));
        pmax = fmaxf(pmax, __shfl_xor(pmax, 32));

        if (!__all(pmax - m_ <= 8.0f)) {
            float mn = fmaxf(m_, pmax);
            float al = __expf(m_ - mn);
            m_ = mn; l_ *= al;
            float alr[4];
            #pragma unroll
            for (int r = 0; r < 4; ++r) alr[r] = __shfl(al, fq * 4 + r);
            #pragma unroll
            for (int dn = 0; dn < 4; ++dn)
                #pragma unroll
                for (int r = 0; r < 4; ++r) po[dn][r] *= alr[r];
        }

        float p[4][4];
        float rs = 0.f;
        #pragma unroll
        for (int jn = 0; jn < 4; ++jn)
            #pragma unroll
            for (int r = 0; r < 4; ++r) {
                p[jn][r] = __expf(fmaf(sa[jn][r], 0.125f, -m_));
                rs += p[jn][r];
            }
        rs += __shfl_xor(rs, 16);
        rs += __shfl_xor(rs, 32);
        l_ += rs;

        // write P row q: 4 consecutive kv per jn -> 2 cvt_pk + 1 ds_write_b64
        #pragma unroll
        for (int jn = 0; jn < 4; ++jn) {
            unsigned pk0, pk1;
            asm("v_cvt_pk_bf16_f32 %0, %1, %2" : "=v"(pk0) : "v"(p[jn][0]), "v"(p[jn][1]));
            asm("v_cvt_pk_bf16_f32 %0, %1, %2" : "=v"(pk1) : "v"(p[jn][2]), "v"(p[jn][3]));
            int slot = (jn * 2 + (fq >> 1)) ^ fx;
            uint2 pw; pw.x = pk0; pw.y = pk1;
            *(uint2*)(Pl + q * 128 + slot * 16 + (fq & 1) * 8) = pw;
        }

        // O += P V (A = P row q, B = V^T) — wave-private Pl rows, same-wave RAW
        #pragma unroll
        for (int ks = 0; ks < 2; ++ks) {
            bf16x8 pf = *(const bf16x8*)(Pl + q * 128 + (((ks * 4 + fq) ^ fx) * 16));
            #pragma unroll
            for (int dn = 0; dn < 4; ++dn) {
                int dr = dn * 16 + fr;
                bf16x8 vf = *(const bf16x8*)(Vl + dr * 128 + (((ks * 4 + fq) ^ fx) * 16));
                po[dn] = MFMA(pf, vf, po[dn]);
            }
        }
    }

    if (fq == 0) {
        mstat[(size_t)bh * S_ + q0 + q] = m_;
        lstat[(size_t)bh * S_ + q0 + q] = l_;
    }
    float inv[4];
    {
        float il = 1.0f / l_;
        #pragma unroll
        for (int r = 0; r < 4; ++r) inv[r] = __shfl(il, fq * 4 + r);
    }
    #pragma unroll
    for (int dn = 0; dn < 4; ++dn) {
        int col = h * 64 + dn * 16 + fr;
        #pragma unroll
        for (int r = 0; r < 4; ++r) {
            int row = q0 + wv * 16 + fq * 4 + r;
            ctxb[(size_t)(b * S_ + row) * D_ + col] = f2bf(po[dn][r] * inv[r]);
        }
    }
}

// ---------------------------------------------------------------------------
// Head-averaged attn weights, swapped-QK: lane owns q-row -> 2 scalar m/l
// loads per head (vs 8) and float4 output stores (vs 16 scalar).
// ---------------------------------------------------------------------------
__global__ __launch_bounds__(256) void attn_wts_mfma(
    const ushort_t* __restrict__ qkvb, const float* __restrict__ mstat,
    const float* __restrict__ lstat, float* __restrict__ attnw)
{
    __shared__ char Ql[64 * 128];
    __shared__ char Kl[64 * 128];
    const int tid = threadIdx.x;
    const int wv = tid >> 6, lane = tid & 63;
    const int fr = lane & 15, fq = lane >> 4;
    const int fx = fr & 7;
    const int b = blockIdx.z;
    const int q0 = blockIdx.y * 64, k0 = blockIdx.x * 64;
    const int srow = tid >> 2, sq = tid & 3;
    const int sb = srow * 128, sxr = srow & 7;
    const int slot0 = (sq * 2) ^ sxr, slot1 = (sq * 2 + 1) ^ sxr;
    const int q = wv * 16 + fr;

    const f32x4 fz = {0.f, 0.f, 0.f, 0.f};
    float wacc[4][4];
    #pragma unroll
    for (int jn = 0; jn < 4; ++jn)
        #pragma unroll
        for (int r = 0; r < 4; ++r) wacc[jn][r] = 0.f;

    for (int h = 0; h < H_; ++h) {
        const ushort_t* Qg = qkvb + (size_t)(b * S_ + q0 + srow) * TRIPLE + h * 64 + sq * 16;
        const ushort_t* Kg = qkvb + (size_t)(b * S_ + k0 + srow) * TRIPLE + 1024 + h * 64 + sq * 16;
        u16x8 qv0 = *(const u16x8*)(Qg);
        u16x8 qv1 = *(const u16x8*)(Qg + 8);
        u16x8 kv0 = *(const u16x8*)(Kg);
        u16x8 kv1 = *(const u16x8*)(Kg + 8);
        __syncthreads();
        *(u16x8*)(Ql + sb + slot0 * 16) = qv0;
        *(u16x8*)(Ql + sb + slot1 * 16) = qv1;
        *(u16x8*)(Kl + sb + slot0 * 16) = kv0;
        *(u16x8*)(Kl + sb + slot1 * 16) = kv1;
        __syncthreads();

        f32x4 sa[4];
        #pragma unroll
        for (int jn = 0; jn < 4; ++jn) sa[jn] = fz;
        #pragma unroll
        for (int ks = 0; ks < 2; ++ks) {
            bf16x8 qfr = *(const bf16x8*)(Ql + q * 128 + (((ks * 4 + fq) ^ fx) * 16));
            #pragma unroll
            for (int jn = 0; jn < 4; ++jn) {
                int kr = jn * 16 + fr;
                bf16x8 kf = *(const bf16x8*)(Kl + kr * 128 + (((ks * 4 + fq) ^ fx) * 16));
                sa[jn] = MFMA(kf, qfr, sa[jn]); // swapped: sa[jn][r] = S[kv][q]
            }
        }

        const float mi = mstat[(size_t)(b * H_ + h) * S_ + q0 + q];
        const float il = 1.0f / lstat[(size_t)(b * H_ + h) * S_ + q0 + q];
        #pragma unroll
        for (int jn = 0; jn < 4; ++jn)
            #pragma unroll
            for (int r = 0; r < 4; ++r)
                wacc[jn][r] += __expf(fmaf(sa[jn][r], 0.125f, -mi)) * il;
    }

    float* dst = attnw + (size_t)b * S_ * S_ + (size_t)(q0 + q) * S_ + k0;
    #pragma unroll
    for (int jn = 0; jn < 4; ++jn) {
        float4 v = make_float4(wacc[jn][0] * 0.0625f, wacc[jn][1] * 0.0625f,
                               wacc[jn][2] * 0.0625f, wacc[jn][3] * 0.0625f);
        *(float4*)(dst + jn * 16 + fq * 4) = v;
    }
}

// ---------------------------------------------------------------------------
// Residual-add + LayerNorm: main input bf16, residual fp32; out fp32 (+bf16).
// ---------------------------------------------------------------------------
__global__ __launch_bounds__(256) void ln_kernel(
    const ushort_t* __restrict__ xin_bf, const float* __restrict__ resid,
    const float* __restrict__ g, const float* __restrict__ bb,
    float* __restrict__ out_f32, ushort_t* __restrict__ out_bf, int write_bf)
{
    const int row = blockIdx.x, tid = threadIdx.x;
    const size_t off = (size_t)row * D_ + tid * 4;
    union { uint2 u2; ushort_t hx[4]; } uu;
    uu.u2 = *(const uint2*)(xin_bf + off);
    float4 rr = *(const float4*)(resid + off);
    float v[4];
    v[0] = bf2f(uu.hx[0]) + rr.x; v[1] = bf2f(uu.hx[1]) + rr.y;
    v[2] = bf2f(uu.hx[2]) + rr.z; v[3] = bf2f(uu.hx[3]) + rr.w;
    float sum = v[0] + v[1] + v[2] + v[3];
    float ssq = v[0]*v[0] + v[1]*v[1] + v[2]*v[2] + v[3]*v[3];
    #pragma unroll
    for (int msk = 1; msk < 64; msk <<= 1) {
        sum += __shfl_xor(sum, msk);
        ssq += __shfl_xor(ssq, msk);
    }
    __shared__ float red[8];
    const int wvi = tid >> 6, ln_ = tid & 63;
    if (ln_ == 0) { red[wvi] = sum; red[4 + wvi] = ssq; }
    __syncthreads();
    sum = red[0] + red[1] + red[2] + red[3];
    ssq = red[4] + red[5] + red[6] + red[7];
    const float mu = sum * (1.0f / D_);
    const float var = ssq * (1.0f / D_) - mu * mu;
    const float rstd = rsqrtf(var + 1e-5f);
    float4 gv = *(const float4*)(g + tid * 4);
    float4 bv = *(const float4*)(bb + tid * 4);
    float o0 = (v[0] - mu) * rstd * gv.x + bv.x;
    float o1 = (v[1] - mu) * rstd * gv.y + bv.y;
    float o2 = (v[2] - mu) * rstd * gv.z + bv.z;
    float o3 = (v[3] - mu) * rstd * gv.w + bv.w;
    *(float4*)(out_f32 + off) = make_float4(o0, o1, o2, o3);
    if (write_bf) {
        union { uint2 u2; ushort_t hx[4]; } ob;
        ob.hx[0] = f2bf(o0); ob.hx[1] = f2bf(o1);
        ob.hx[2] = f2bf(o2); ob.hx[3] = f2bf(o3);
        *(uint2*)(out_bf + off) = ob.u2;
    }
}

// ---------------------------------------------------------------------------
extern "C" void kernel_launch(void* const* d_in, const int* in_sizes, int n_in,
                              void* d_out, int out_size, void* d_ws, size_t ws_size,
                              hipStream_t stream)
{
    (void)in_sizes; (void)n_in; (void)out_size; (void)ws_size;
    const float* x    = (const float*)d_in[0];
    const float* wqkv = (const float*)d_in[1];
    const float* bqkv = (const float*)d_in[2];
    const float* wo   = (const float*)d_in[3];
    const float* bo   = (const float*)d_in[4];
    const float* lng  = (const float*)d_in[5];
    const float* lnb  = (const float*)d_in[6];
    const float* w1   = (const float*)d_in[7];
    const float* b1   = (const float*)d_in[8];
    const float* w2   = (const float*)d_in[9];
    const float* b2   = (const float*)d_in[10];

    float* outp  = (float*)d_out;
    float* attnw = outp + (size_t)B_ * S_ * D_;

    char* wsb = (char*)d_ws;
    ushort_t* qkvb  = (ushort_t*)(wsb);
    ushort_t* vT    = (ushort_t*)(wsb + ((size_t)48 << 20));
    ushort_t* ff2b  = vT;
    ushort_t* ctxb  = (ushort_t*)(wsb + ((size_t)64 << 20));
    ushort_t* attdb = (ushort_t*)(wsb + ((size_t)80 << 20));
    float*    hf    = (float*)(wsb + ((size_t)96 << 20));
    ushort_t* hbf   = (ushort_t*)(wsb + ((size_t)128 << 20));
    ushort_t* xb    = (ushort_t*)(wsb + ((size_t)144 << 20));
    ushort_t* ff1b  = xb;
    ushort_t* wqkvb = (ushort_t*)(wsb + ((size_t)176 << 20));
    ushort_t* wob   = (ushort_t*)(wsb + ((size_t)182 << 20));
    ushort_t* w1b   = (ushort_t*)(wsb + ((size_t)184 << 20));
    ushort_t* w2b   = (ushort_t*)(wsb + ((size_t)188 << 20));
    float*    mst   = (float*)(wsb + ((size_t)192 << 20));
    float*    lst   = (float*)(wsb + ((size_t)192 << 20) + ((size_t)512 << 10));

    dim3 blk(256);

    castk<<<dim3(8388608 / 2048), blk, 0, stream>>>(x, xb, 8388608);
    castk<<<dim3(3145728 / 2048), blk, 0, stream>>>(wqkv, wqkvb, 3145728);
    castk<<<dim3(1048576 / 2048), blk, 0, stream>>>(wo, wob, 1048576);
    castk<<<dim3(2097152 / 2048), blk, 0, stream>>>(w1, w1b, 2097152);
    castk<<<dim3(2097152 / 2048), blk, 0, stream>>>(w2, w2b, 2097152);

    gemm_bf16<<<dim3(24, 64), blk, 0, stream>>>(xb, wqkvb, bqkv, qkvb, 3072, 1024, 0);
    vtrans<<<dim3(32, 64), blk, 0, stream>>>(qkvb, vT);
    attn_ctx_mfma<<<dim3(32, 64), blk, 0, stream>>>(qkvb, vT, ctxb, mst, lst);
    attn_wts_mfma<<<dim3(32, 32, 4), blk, 0, stream>>>(qkvb, mst, lst, attnw);
    gemm_bf16<<<dim3(8, 64), blk, 0, stream>>>(ctxb, wob, bo, attdb, 1024, 1024, 0);
    ln_kernel<<<dim3(8192), blk, 0, stream>>>(attdb, x, lng, lnb, hf, hbf, 1);
    gemm_bf16<<<dim3(16, 64), blk, 0, stream>>>(hbf, w1b, b1, ff1b, 2048, 1024, 1);
    gemm_bf16<<<dim3(8, 64), blk, 0, stream>>>(ff1b, w2b, b2, ff2b, 1024, 2048, 0);
    ln_kernel<<<dim3(8192), blk, 0, stream>>>(ff2b, hf, lng, lnb, outp, (ushort_t*)0, 0);
}